// Round 2
// baseline (437.687 us; speedup 1.0000x reference)
//
#include <hip/hip_runtime.h>

#define DEV __device__ __forceinline__

typedef short short4v __attribute__((ext_vector_type(4)));
typedef short short8v __attribute__((ext_vector_type(8)));
typedef float float4v __attribute__((ext_vector_type(4)));
typedef unsigned short u16;

DEV unsigned short f2bf(float f) {
  unsigned u = __builtin_bit_cast(unsigned, f);
  u += 0x7fffu + ((u >> 16) & 1u);
  return (unsigned short)(u >> 16);
}
DEV float bf2f(unsigned short h) {
  unsigned u = ((unsigned)h) << 16;
  return __builtin_bit_cast(float, u);
}
DEV float4v mfma32(short8v a, short8v b, float4v c) {
  return __builtin_amdgcn_mfma_f32_16x16x32_bf16(a, b, c, 0, 0, 0);
}
DEV float4v mfma16(short4v a, short4v b, float4v c) {
  return __builtin_amdgcn_mfma_f32_16x16x16bf16_1k(a, b, c, 0, 0, 0);
}
DEV void async16(const void* g, void* l) {
  __builtin_amdgcn_global_load_lds(
      (const __attribute__((address_space(1))) unsigned*)g,
      (__attribute__((address_space(3))) unsigned*)l, 16, 0, 0);
}
DEV short4v cvt4(float4v v) {
  short4v r;
  r[0] = (short)f2bf(v[0]); r[1] = (short)f2bf(v[1]);
  r[2] = (short)f2bf(v[2]); r[3] = (short)f2bf(v[3]);
  return r;
}

// ---------------- input conversion f32 -> bf16 ----------------
__global__ __launch_bounds__(256)
void cvt_in(const float* __restrict__ q, const float* __restrict__ kv,
            u16* __restrict__ qb, u16* __restrict__ kvb) {
  const float* src = blockIdx.y ? kv : q;
  u16* dst = blockIdx.y ? kvb : qb;
  size_t i = ((size_t)blockIdx.x * 256 + threadIdx.x) * 8;
  float4v a = *(const float4v*)(src + i);
  float4v b = *(const float4v*)(src + i + 4);
  short8v o;
  o[0] = (short)f2bf(a[0]); o[1] = (short)f2bf(a[1]);
  o[2] = (short)f2bf(a[2]); o[3] = (short)f2bf(a[3]);
  o[4] = (short)f2bf(b[0]); o[5] = (short)f2bf(b[1]);
  o[6] = (short)f2bf(b[2]); o[7] = (short)f2bf(b[3]);
  *(short8v*)(dst + i) = o;
}

// ------------- weight convert + transpose: dst[c*R + r] = src[r*C + c] -------------
__global__ __launch_bounds__(256)
void cvt_w(const float* Wq, const float* Wk, const float* Wv, const float* Wo,
           const float* W1, const float* W2,
           u16* Wqt, u16* Wkt, u16* Wvt, u16* Wot, u16* W1t, u16* W2t) {
  const float* src; u16* dst; int R, C;
  switch (blockIdx.y) {
    case 0: src = Wq; dst = Wqt; R = 256;  C = 256;  break;
    case 1: src = Wk; dst = Wkt; R = 256;  C = 256;  break;
    case 2: src = Wv; dst = Wvt; R = 256;  C = 256;  break;
    case 3: src = Wo; dst = Wot; R = 256;  C = 256;  break;
    case 4: src = W1; dst = W1t; R = 256;  C = 1024; break;
    default: src = W2; dst = W2t; R = 1024; C = 256; break;
  }
  int i = blockIdx.x * 256 + threadIdx.x;
  if (i < R * C) {
    int r = i % R, c = i / R;
    dst[i] = f2bf(src[(size_t)r * C + c]);
  }
}

// ---------------- 128x128-tile GEMM: out = A @ Wt^T + bias (+resid) ----------------
// A: [M][K] bf16, Wt: [N][K] bf16, out: [M][N] bf16. BK=64 (128B LDS rows).
template<bool RESID>
__global__ __launch_bounds__(256, 2)
void gemm128(const u16* __restrict__ A, const u16* __restrict__ Wt,
             const float* __restrict__ bias, const float* __restrict__ resid,
             u16* __restrict__ out, int M, int N, int K) {
  __shared__ alignas(16) char sm[32768];
  char* sa = sm;
  char* sb = sm + 16384;
  const int tid = threadIdx.x;
  const int w = tid >> 6, lane = tid & 63;
  const int ln15 = lane & 15, gq = lane >> 4;
  const int wr = w >> 1, wc = w & 1;
  const int m0 = blockIdx.x * 128, n0 = blockIdx.y * 128;
  const char* Ab = (const char*)A;
  const char* Wb = (const char*)Wt;
  const int Kb = K * 2;  // row bytes

  float4v acc[4][4] = {};
  const int nk = K >> 6;
  for (int kk = 0; kk < nk; ++kk) {
    #pragma unroll
    for (int p = 0; p < 4; ++p) {
      int L = p * 4096 + w * 1024 + lane * 16;
      int row = L >> 7, colb = L & 127;
      int sw = colb ^ ((row & 7) << 4);
      async16(Ab + (size_t)(m0 + row) * Kb + kk * 128 + sw, sa + p * 4096 + w * 1024);
      async16(Wb + (size_t)(n0 + row) * Kb + kk * 128 + sw, sb + p * 4096 + w * 1024);
    }
    __syncthreads();
    #pragma unroll
    for (int ks = 0; ks < 2; ++ks) {
      short8v af[4], bfr[4];
      #pragma unroll
      for (int mf = 0; mf < 4; ++mf) {
        int r = wr * 64 + mf * 16 + ln15;
        af[mf] = *(const short8v*)(sa + r * 128 + ((ks * 64 + gq * 16) ^ ((r & 7) << 4)));
      }
      #pragma unroll
      for (int nf = 0; nf < 4; ++nf) {
        int r = wc * 64 + nf * 16 + ln15;
        bfr[nf] = *(const short8v*)(sb + r * 128 + ((ks * 64 + gq * 16) ^ ((r & 7) << 4)));
      }
      #pragma unroll
      for (int mf = 0; mf < 4; ++mf)
        #pragma unroll
        for (int nf = 0; nf < 4; ++nf)
          acc[mf][nf] = mfma32(af[mf], bfr[nf], acc[mf][nf]);
    }
    __syncthreads();
  }
  #pragma unroll
  for (int nf = 0; nf < 4; ++nf) {
    int col = n0 + wc * 64 + nf * 16 + ln15;
    float bb = bias[col];
    #pragma unroll
    for (int mf = 0; mf < 4; ++mf) {
      int rb = m0 + wr * 64 + mf * 16 + 4 * gq;
      #pragma unroll
      for (int j = 0; j < 4; ++j) {
        size_t idx = (size_t)(rb + j) * N + col;
        float v = acc[mf][nf][j] + bb;
        if (RESID) v += resid[idx];
        out[idx] = f2bf(v);
      }
    }
  }
}

// ---------------- windowed attention, one block per (window, head, q-half) ----------------
// Q,K,V: [65536][256] bf16 (head slice at h*32). ctx out same layout.
__global__ __launch_bounds__(256, 2)
void attn_kernel(const u16* __restrict__ Qg, const u16* __restrict__ Kg,
                 const u16* __restrict__ Vg, u16* __restrict__ ctx) {
  __shared__ alignas(16) char vs[256 * 80];  // V tile, 80B padded rows (conflict-free)
  const int bw = blockIdx.x;
  const int win = bw >> 4, head = (bw >> 1) & 7, qh = bw & 1;
  const int tid = threadIdx.x;
  const int w = tid >> 6, lane = tid & 63;
  const int ln15 = lane & 15, gq = lane >> 4;
  const int tok0 = win << 8;
  const int q0 = qh * 128 + w * 32;

  // stage V [256][32] into padded LDS
  {
    const u16* src = Vg + (size_t)(tok0 + tid) * 256 + head * 32;
    char* dst = vs + tid * 80;
    #pragma unroll
    for (int i = 0; i < 4; ++i)
      *(short8v*)(dst + i * 16) = *(const short8v*)(src + i * 8);
  }

  // Q B-fragments (2 x 16 q-cols), direct from global
  short8v qf[2];
  #pragma unroll
  for (int qi = 0; qi < 2; ++qi)
    qf[qi] = *(const short8v*)(Qg + (size_t)(tok0 + q0 + qi * 16 + ln15) * 256 + head * 32 + gq * 8);

  // S^T = K @ Q^T  (16 key-frags x 2 q-frags), dh=32 -> single MFMA each
  float4v s[16][2];
  #pragma unroll
  for (int kf = 0; kf < 16; ++kf) {
    short8v kfr = *(const short8v*)(Kg + (size_t)(tok0 + kf * 16 + ln15) * 256 + head * 32 + gq * 8);
    float4v z = {0.f, 0.f, 0.f, 0.f};
    s[kf][0] = mfma32(kfr, qf[0], z);
    s[kf][1] = mfma32(kfr, qf[1], z);
  }
  __syncthreads();  // V staged

  // softmax over k (rows of S^T): per-lane 64 vals + 4-lane reduce (xor 16,32)
  const float KSC = (float)(1.4426950408889634 / 5.656854249492381);  // log2e/sqrt(32)
  float rs[2];
  #pragma unroll
  for (int qi = 0; qi < 2; ++qi) {
    float mx = -1e30f;
    #pragma unroll
    for (int kf = 0; kf < 16; ++kf)
      #pragma unroll
      for (int j = 0; j < 4; ++j) mx = fmaxf(mx, s[kf][qi][j]);
    mx = fmaxf(mx, __shfl_xor(mx, 16));
    mx = fmaxf(mx, __shfl_xor(mx, 32));
    float sum = 0.f;
    #pragma unroll
    for (int kf = 0; kf < 16; ++kf)
      #pragma unroll
      for (int j = 0; j < 4; ++j) {
        float p = exp2f((s[kf][qi][j] - mx) * KSC);
        s[kf][qi][j] = p;
        sum += p;
      }
    sum += __shfl_xor(sum, 16);
    sum += __shfl_xor(sum, 32);
    rs[qi] = 1.0f / sum;
  }

  // ctx^T = V^T @ P^T via 16x16x16 (P^T frags feed B-operand lane-for-lane)
  float4v cacc[2][2] = {};  // [df][qi]
  #pragma unroll
  for (int ks = 0; ks < 16; ++ks) {
    short4v pb[2];
    pb[0] = cvt4(s[ks][0]);
    pb[1] = cvt4(s[ks][1]);
    #pragma unroll
    for (int df = 0; df < 2; ++df) {
      const char* vb = vs + (size_t)(16 * ks + 4 * gq) * 80 + (df * 16 + ln15) * 2;
      short4v va;
      va[0] = *(const short*)(vb);
      va[1] = *(const short*)(vb + 80);
      va[2] = *(const short*)(vb + 160);
      va[3] = *(const short*)(vb + 240);
      cacc[df][0] = mfma16(va, pb[0], cacc[df][0]);
      cacc[df][1] = mfma16(va, pb[1], cacc[df][1]);
    }
  }

  // scale by 1/sum and store (d contiguous 4 -> 8B stores)
  #pragma unroll
  for (int qi = 0; qi < 2; ++qi)
    #pragma unroll
    for (int df = 0; df < 2; ++df) {
      short4v o;
      #pragma unroll
      for (int j = 0; j < 4; ++j) o[j] = (short)f2bf(cacc[df][qi][j] * rs[qi]);
      *(short4v*)(ctx + (size_t)(tok0 + q0 + qi * 16 + ln15) * 256 + head * 32 + df * 16 + 4 * gq) = o;
    }
}

// ---------------- row-wise LayerNorm in place (bf16), one wave per row ----------------
__global__ __launch_bounds__(256, 4)
void ln_rows(u16* __restrict__ x, const float* __restrict__ g, const float* __restrict__ b) {
  int row = blockIdx.x * 4 + (threadIdx.x >> 6);
  int lane = threadIdx.x & 63;
  u16* p = x + (size_t)row * 256 + lane * 4;
  short4v v = *(short4v*)p;
  float f[4];
  #pragma unroll
  for (int i = 0; i < 4; ++i) f[i] = bf2f((unsigned short)v[i]);
  float s = f[0] + f[1] + f[2] + f[3];
  float ss = f[0] * f[0] + f[1] * f[1] + f[2] * f[2] + f[3] * f[3];
  #pragma unroll
  for (int m = 1; m <= 32; m <<= 1) {
    s += __shfl_xor(s, m);
    ss += __shfl_xor(ss, m);
  }
  float mu = s * (1.f / 256.f);
  float var = ss * (1.f / 256.f) - mu * mu;
  float rstd = rsqrtf(var + 1e-5f);
  #pragma unroll
  for (int i = 0; i < 4; ++i) {
    int c = lane * 4 + i;
    float o = (f[i] - mu) * rstd * g[c] + b[c];
    v[i] = (short)f2bf(o);
  }
  *(short4v*)p = v;
}

// ---------------- fused FFN + residual + LN2: out = LN2(x + relu(x@W1+b1)@W2 + b2) ----------------
// x: [65536][256] bf16; W1t: [1024][256] bf16; W2t: [256][1024] bf16; out f32.
__global__ __launch_bounds__(256, 1)
void ffn_fused(const u16* __restrict__ X, const u16* __restrict__ W1t,
               const u16* __restrict__ W2t, const float* __restrict__ b1,
               const float* __restrict__ b2, const float* __restrict__ g2,
               const float* __restrict__ be2, float* __restrict__ out) {
  __shared__ alignas(16) char sm[108544];
  char* xs  = sm;           // [64][512B]
  char* w1c = sm + 32768;   // [64][512B]
  char* w2c = sm + 65536;   // [256][128B]
  char* h1c = sm + 98304;   // [64][128B]
  float* red = (float*)(sm + 106496);  // [4][64][2]
  const int tid = threadIdx.x;
  const int w = tid >> 6, lane = tid & 63;
  const int ln15 = lane & 15, gq = lane >> 4;
  const int wr = w >> 1, wc = w & 1;
  const int m0 = blockIdx.x * 64;

  // stage x tile once
  #pragma unroll
  for (int p = 0; p < 8; ++p) {
    int L = p * 4096 + w * 1024 + lane * 16;
    int row = L >> 9, colb = L & 511;
    async16((const char*)X + (size_t)(m0 + row) * 512 + (colb ^ ((row & 7) << 4)),
            xs + p * 4096 + w * 1024);
  }

  float4v ff[4][4] = {};  // persistent accum, wave w owns cols [w*64, w*64+64)
  for (int c = 0; c < 16; ++c) {
    // stage W1 chunk (rows c*64..+64 of W1t) and W2 chunk (cols c*64..+64 of W2t)
    #pragma unroll
    for (int p = 0; p < 8; ++p) {
      int L = p * 4096 + w * 1024 + lane * 16;
      {
        int row = L >> 9, colb = L & 511;
        async16((const char*)W1t + (size_t)(c * 64 + row) * 512 + (colb ^ ((row & 7) << 4)),
                w1c + p * 4096 + w * 1024);
      }
      {
        int row = L >> 7, colb = L & 127;
        async16((const char*)W2t + (size_t)row * 2048 + c * 128 + (colb ^ ((row & 7) << 4)),
                w2c + p * 4096 + w * 1024);
      }
    }
    __syncthreads();

    // GEMM1: h1c[64][64] = relu(x @ W1c^T + b1), wave does 32x32
    float4v g1[2][2] = {};
    #pragma unroll
    for (int ks = 0; ks < 8; ++ks) {
      short8v xa[2], wb[2];
      #pragma unroll
      for (int mf = 0; mf < 2; ++mf) {
        int r = wr * 32 + mf * 16 + ln15;
        xa[mf] = *(const short8v*)(xs + r * 512 + ((ks * 64 + gq * 16) ^ ((r & 7) << 4)));
      }
      #pragma unroll
      for (int nf = 0; nf < 2; ++nf) {
        int r = wc * 32 + nf * 16 + ln15;
        wb[nf] = *(const short8v*)(w1c + r * 512 + ((ks * 64 + gq * 16) ^ ((r & 7) << 4)));
      }
      #pragma unroll
      for (int mf = 0; mf < 2; ++mf)
        #pragma unroll
        for (int nf = 0; nf < 2; ++nf)
          g1[mf][nf] = mfma32(xa[mf], wb[nf], g1[mf][nf]);
    }
    #pragma unroll
    for (int nf = 0; nf < 2; ++nf) {
      int f = wc * 32 + nf * 16 + ln15;
      float bb = b1[c * 64 + f];
      #pragma unroll
      for (int mf = 0; mf < 2; ++mf)
        #pragma unroll
        for (int j = 0; j < 4; ++j) {
          int r = wr * 32 + mf * 16 + 4 * gq + j;
          float v = g1[mf][nf][j] + bb;
          v = v > 0.f ? v : 0.f;
          *(u16*)(h1c + r * 128 + ((f * 2) ^ ((r & 7) << 4))) = f2bf(v);
        }
    }
    __syncthreads();

    // GEMM2: ff += h1c @ W2c^T, wave covers all 64 rows x its 64 cols
    #pragma unroll
    for (int ks = 0; ks < 2; ++ks) {
      short8v ha[4], wb2[4];
      #pragma unroll
      for (int mf = 0; mf < 4; ++mf) {
        int r = mf * 16 + ln15;
        ha[mf] = *(const short8v*)(h1c + r * 128 + ((ks * 64 + gq * 16) ^ ((r & 7) << 4)));
      }
      #pragma unroll
      for (int nf = 0; nf < 4; ++nf) {
        int n = w * 64 + nf * 16 + ln15;
        wb2[nf] = *(const short8v*)(w2c + n * 128 + ((ks * 64 + gq * 16) ^ ((n & 7) << 4)));
      }
      #pragma unroll
      for (int mf = 0; mf < 4; ++mf)
        #pragma unroll
        for (int nf = 0; nf < 4; ++nf)
          ff[mf][nf] = mfma32(ha[mf], wb2[nf], ff[mf][nf]);
    }
    __syncthreads();
  }

  // epilogue: v = ff + b2 + x; LN2 across 256 cols (cross-wave via LDS partials)
  float b2v[4], g2v[4], be2v[4];
  #pragma unroll
  for (int nf = 0; nf < 4; ++nf) {
    int col = w * 64 + nf * 16 + ln15;
    b2v[nf] = b2[col];
    g2v[nf] = g2[col];
    be2v[nf] = be2[col];
  }
  #pragma unroll
  for (int mf = 0; mf < 4; ++mf)
    #pragma unroll
    for (int j = 0; j < 4; ++j) {
      int row = mf * 16 + 4 * gq + j;
      float sum = 0.f, sq = 0.f;
      #pragma unroll
      for (int nf = 0; nf < 4; ++nf) {
        int col = w * 64 + nf * 16 + ln15;
        float xv = bf2f(*(const u16*)(xs + row * 512 + ((col * 2) ^ ((row & 7) << 4))));
        float v = ff[mf][nf][j] + b2v[nf] + xv;
        ff[mf][nf][j] = v;
        sum += v;
        sq += v * v;
      }
      #pragma unroll
      for (int m = 1; m <= 8; m <<= 1) {
        sum += __shfl_xor(sum, m);
        sq += __shfl_xor(sq, m);
      }
      if (ln15 == 0) {
        red[(w * 64 + row) * 2] = sum;
        red[(w * 64 + row) * 2 + 1] = sq;
      }
    }
  __syncthreads();
  #pragma unroll
  for (int mf = 0; mf < 4; ++mf)
    #pragma unroll
    for (int j = 0; j < 4; ++j) {
      int row = mf * 16 + 4 * gq + j;
      float S = 0.f, S2 = 0.f;
      #pragma unroll
      for (int wv = 0; wv < 4; ++wv) {
        S += red[(wv * 64 + row) * 2];
        S2 += red[(wv * 64 + row) * 2 + 1];
      }
      float mu = S * (1.f / 256.f);
      float var = S2 * (1.f / 256.f) - mu * mu;
      float rstd = rsqrtf(var + 1e-5f);
      #pragma unroll
      for (int nf = 0; nf < 4; ++nf) {
        int col = w * 64 + nf * 16 + ln15;
        out[(size_t)(m0 + row) * 256 + col] = (ff[mf][nf][j] - mu) * rstd * g2v[nf] + be2v[nf];
      }
    }
}

extern "C" void kernel_launch(void* const* d_in, const int* in_sizes, int n_in,
                              void* d_out, int out_size, void* d_ws, size_t ws_size,
                              hipStream_t stream) {
  (void)in_sizes; (void)n_in; (void)out_size;
  const float* query = (const float*)d_in[0];
  const float* kv    = (const float*)d_in[1];
  const float* Wqm = (const float*)d_in[2];  const float* bq = (const float*)d_in[3];
  const float* Wkm = (const float*)d_in[4];  const float* bk = (const float*)d_in[5];
  const float* Wvm = (const float*)d_in[6];  const float* bv = (const float*)d_in[7];
  const float* Wom = (const float*)d_in[8];  const float* bo = (const float*)d_in[9];
  const float* ln1g = (const float*)d_in[10]; const float* ln1b = (const float*)d_in[11];
  const float* W1m = (const float*)d_in[12]; const float* b1 = (const float*)d_in[13];
  const float* W2m = (const float*)d_in[14]; const float* b2 = (const float*)d_in[15];
  const float* ln2g = (const float*)d_in[16]; const float* ln2b = (const float*)d_in[17];
  float* out = (float*)d_out;

  char* ws = (char*)d_ws;
  const size_t MB = 1ull << 20;
  if (ws_size < 130 * MB) return;  // avoid OOB if workspace too small

  // lifetime-aliased layout (all bf16):
  u16* qbf  = (u16*)(ws);            // [0,32M)  input q bf16; dead after Q-proj
  u16* kvbf = (u16*)(ws + 32 * MB);  // [32,64M) input kv bf16; dead after V-proj
  u16* Vw   = (u16*)(ws);            // aliases qbf
  u16* ctxw = (u16*)(ws + 32 * MB);  // aliases kvbf
  u16* Qw   = (u16*)(ws + 64 * MB);  // dead after attn
  u16* xw   = (u16*)(ws + 64 * MB);  // aliases Qw
  u16* Kw   = (u16*)(ws + 96 * MB);
  char* wb = ws + 128 * MB;
  u16* Wqt = (u16*)(wb);
  u16* Wkt = (u16*)(wb + 131072);
  u16* Wvt = (u16*)(wb + 262144);
  u16* Wot = (u16*)(wb + 393216);
  u16* W1t = (u16*)(wb + 524288);
  u16* W2t = (u16*)(wb + 1048576);

  cvt_in<<<dim3(8192, 2), 256, 0, stream>>>(query, kv, qbf, kvbf);
  cvt_w<<<dim3(1024, 6), 256, 0, stream>>>(Wqm, Wkm, Wvm, Wom, W1m, W2m,
                                           Wqt, Wkt, Wvt, Wot, W1t, W2t);
  gemm128<false><<<dim3(512, 2), 256, 0, stream>>>(qbf,  Wqt, bq, nullptr, Qw, 65536, 256, 256);
  gemm128<false><<<dim3(512, 2), 256, 0, stream>>>(kvbf, Wkt, bk, nullptr, Kw, 65536, 256, 256);
  gemm128<false><<<dim3(512, 2), 256, 0, stream>>>(kvbf, Wvt, bv, nullptr, Vw, 65536, 256, 256);
  attn_kernel<<<dim3(4096), 256, 0, stream>>>(Qw, Kw, Vw, ctxw);
  gemm128<true><<<dim3(512, 2), 256, 0, stream>>>(ctxw, Wot, bo, query, xw, 65536, 256, 256);
  ln_rows<<<dim3(16384), 256, 0, stream>>>(xw, ln1g, ln1b);
  ffn_fused<<<dim3(1024), 256, 0, stream>>>(xw, W1t, W2t, b1, b2, ln2g, ln2b, out);
}

// Round 3
// 403.658 us; speedup vs baseline: 1.0843x; 1.0843x over previous
//
#include <hip/hip_runtime.h>

#define DEV __device__ __forceinline__

typedef short short4v __attribute__((ext_vector_type(4)));
typedef short short8v __attribute__((ext_vector_type(8)));
typedef float float4v __attribute__((ext_vector_type(4)));
typedef unsigned short u16;

DEV unsigned short f2bf(float f) {
  unsigned u = __builtin_bit_cast(unsigned, f);
  u += 0x7fffu + ((u >> 16) & 1u);
  return (unsigned short)(u >> 16);
}
DEV float bf2f(unsigned short h) {
  unsigned u = ((unsigned)h) << 16;
  return __builtin_bit_cast(float, u);
}
DEV float4v mfma32(short8v a, short8v b, float4v c) {
  return __builtin_amdgcn_mfma_f32_16x16x32_bf16(a, b, c, 0, 0, 0);
}
DEV float4v mfma16(short4v a, short4v b, float4v c) {
  return __builtin_amdgcn_mfma_f32_16x16x16bf16_1k(a, b, c, 0, 0, 0);
}
DEV void async16(const void* g, void* l) {
  __builtin_amdgcn_global_load_lds(
      (const __attribute__((address_space(1))) unsigned*)g,
      (__attribute__((address_space(3))) unsigned*)l, 16, 0, 0);
}
DEV short4v cvt4(float4v v) {
  short4v r;
  r[0] = (short)f2bf(v[0]); r[1] = (short)f2bf(v[1]);
  r[2] = (short)f2bf(v[2]); r[3] = (short)f2bf(v[3]);
  return r;
}

// ---------------- input conversion f32 -> bf16 ----------------
__global__ __launch_bounds__(256)
void cvt_in(const float* __restrict__ q, const float* __restrict__ kv,
            u16* __restrict__ qb, u16* __restrict__ kvb) {
  const float* src = blockIdx.y ? kv : q;
  u16* dst = blockIdx.y ? kvb : qb;
  size_t i = ((size_t)blockIdx.x * 256 + threadIdx.x) * 8;
  float4v a = *(const float4v*)(src + i);
  float4v b = *(const float4v*)(src + i + 4);
  short8v o;
  o[0] = (short)f2bf(a[0]); o[1] = (short)f2bf(a[1]);
  o[2] = (short)f2bf(a[2]); o[3] = (short)f2bf(a[3]);
  o[4] = (short)f2bf(b[0]); o[5] = (short)f2bf(b[1]);
  o[6] = (short)f2bf(b[2]); o[7] = (short)f2bf(b[3]);
  *(short8v*)(dst + i) = o;
}

// ------------- weight convert + transpose: dst[c*R + r] = src[r*C + c] -------------
__global__ __launch_bounds__(256)
void cvt_w(const float* Wq, const float* Wk, const float* Wv, const float* Wo,
           const float* W1, const float* W2,
           u16* Wqt, u16* Wkt, u16* Wvt, u16* Wot, u16* W1t, u16* W2t) {
  const float* src; u16* dst; int R, C;
  switch (blockIdx.y) {
    case 0: src = Wq; dst = Wqt; R = 256;  C = 256;  break;
    case 1: src = Wk; dst = Wkt; R = 256;  C = 256;  break;
    case 2: src = Wv; dst = Wvt; R = 256;  C = 256;  break;
    case 3: src = Wo; dst = Wot; R = 256;  C = 256;  break;
    case 4: src = W1; dst = W1t; R = 256;  C = 1024; break;
    default: src = W2; dst = W2t; R = 1024; C = 256; break;
  }
  int i = blockIdx.x * 256 + threadIdx.x;
  if (i < R * C) {
    int r = i % R, c = i / R;
    dst[i] = f2bf(src[(size_t)r * C + c]);
  }
}

// ---------------- 128x128-tile GEMM: out = A @ Wt^T + bias (+resid) ----------------
// A: [M][K] bf16, Wt: [N][K] bf16, out: [M][N] bf16. BK=64 (128B LDS rows).
template<bool RESID>
__global__ __launch_bounds__(256, 2)
void gemm128(const u16* __restrict__ A, const u16* __restrict__ Wt,
             const float* __restrict__ bias, const float* __restrict__ resid,
             u16* __restrict__ out, int M, int N, int K) {
  __shared__ alignas(16) char sm[32768];
  char* sa = sm;
  char* sb = sm + 16384;
  const int tid = threadIdx.x;
  const int w = tid >> 6, lane = tid & 63;
  const int ln15 = lane & 15, gq = lane >> 4;
  const int wr = w >> 1, wc = w & 1;
  const int m0 = blockIdx.x * 128, n0 = blockIdx.y * 128;
  const char* Ab = (const char*)A;
  const char* Wb = (const char*)Wt;
  const int Kb = K * 2;  // row bytes

  float4v acc[4][4] = {};
  const int nk = K >> 6;
  for (int kk = 0; kk < nk; ++kk) {
    #pragma unroll
    for (int p = 0; p < 4; ++p) {
      int L = p * 4096 + w * 1024 + lane * 16;
      int row = L >> 7, colb = L & 127;
      int sw = colb ^ ((row & 7) << 4);
      async16(Ab + (size_t)(m0 + row) * Kb + kk * 128 + sw, sa + p * 4096 + w * 1024);
      async16(Wb + (size_t)(n0 + row) * Kb + kk * 128 + sw, sb + p * 4096 + w * 1024);
    }
    __syncthreads();
    #pragma unroll
    for (int ks = 0; ks < 2; ++ks) {
      short8v af[4], bfr[4];
      #pragma unroll
      for (int mf = 0; mf < 4; ++mf) {
        int r = wr * 64 + mf * 16 + ln15;
        af[mf] = *(const short8v*)(sa + r * 128 + ((ks * 64 + gq * 16) ^ ((r & 7) << 4)));
      }
      #pragma unroll
      for (int nf = 0; nf < 4; ++nf) {
        int r = wc * 64 + nf * 16 + ln15;
        bfr[nf] = *(const short8v*)(sb + r * 128 + ((ks * 64 + gq * 16) ^ ((r & 7) << 4)));
      }
      #pragma unroll
      for (int mf = 0; mf < 4; ++mf)
        #pragma unroll
        for (int nf = 0; nf < 4; ++nf)
          acc[mf][nf] = mfma32(af[mf], bfr[nf], acc[mf][nf]);
    }
    __syncthreads();
  }
  #pragma unroll
  for (int nf = 0; nf < 4; ++nf) {
    int col = n0 + wc * 64 + nf * 16 + ln15;
    float bb = bias[col];
    #pragma unroll
    for (int mf = 0; mf < 4; ++mf) {
      int rb = m0 + wr * 64 + mf * 16 + 4 * gq;
      #pragma unroll
      for (int j = 0; j < 4; ++j) {
        size_t idx = (size_t)(rb + j) * N + col;
        float v = acc[mf][nf][j] + bb;
        if (RESID) v += resid[idx];
        out[idx] = f2bf(v);
      }
    }
  }
}

// ---------------- windowed attention, one block per (window, head, q-half) ----------------
// Q,K,V: [65536][256] bf16 (head slice at h*32). ctx out same layout.
__global__ __launch_bounds__(256, 2)
void attn_kernel(const u16* __restrict__ Qg, const u16* __restrict__ Kg,
                 const u16* __restrict__ Vg, u16* __restrict__ ctx) {
  __shared__ alignas(16) char vs[256 * 80];  // V tile, 80B padded rows (conflict-free)
  const int bw = blockIdx.x;
  const int win = bw >> 4, head = (bw >> 1) & 7, qh = bw & 1;
  const int tid = threadIdx.x;
  const int w = tid >> 6, lane = tid & 63;
  const int ln15 = lane & 15, gq = lane >> 4;
  const int tok0 = win << 8;
  const int q0 = qh * 128 + w * 32;

  // stage V [256][32] into padded LDS
  {
    const u16* src = Vg + (size_t)(tok0 + tid) * 256 + head * 32;
    char* dst = vs + tid * 80;
    #pragma unroll
    for (int i = 0; i < 4; ++i)
      *(short8v*)(dst + i * 16) = *(const short8v*)(src + i * 8);
  }

  // Q B-fragments (2 x 16 q-cols), direct from global
  short8v qf[2];
  #pragma unroll
  for (int qi = 0; qi < 2; ++qi)
    qf[qi] = *(const short8v*)(Qg + (size_t)(tok0 + q0 + qi * 16 + ln15) * 256 + head * 32 + gq * 8);

  // S^T = K @ Q^T  (16 key-frags x 2 q-frags), dh=32 -> single MFMA each
  float4v s[16][2];
  #pragma unroll
  for (int kf = 0; kf < 16; ++kf) {
    short8v kfr = *(const short8v*)(Kg + (size_t)(tok0 + kf * 16 + ln15) * 256 + head * 32 + gq * 8);
    float4v z = {0.f, 0.f, 0.f, 0.f};
    s[kf][0] = mfma32(kfr, qf[0], z);
    s[kf][1] = mfma32(kfr, qf[1], z);
  }
  __syncthreads();  // V staged

  // softmax over k (rows of S^T): per-lane 64 vals + 4-lane reduce (xor 16,32)
  const float KSC = (float)(1.4426950408889634 / 5.656854249492381);  // log2e/sqrt(32)
  float rs[2];
  #pragma unroll
  for (int qi = 0; qi < 2; ++qi) {
    float mx = -1e30f;
    #pragma unroll
    for (int kf = 0; kf < 16; ++kf)
      #pragma unroll
      for (int j = 0; j < 4; ++j) mx = fmaxf(mx, s[kf][qi][j]);
    mx = fmaxf(mx, __shfl_xor(mx, 16));
    mx = fmaxf(mx, __shfl_xor(mx, 32));
    float sum = 0.f;
    #pragma unroll
    for (int kf = 0; kf < 16; ++kf)
      #pragma unroll
      for (int j = 0; j < 4; ++j) {
        float p = exp2f((s[kf][qi][j] - mx) * KSC);
        s[kf][qi][j] = p;
        sum += p;
      }
    sum += __shfl_xor(sum, 16);
    sum += __shfl_xor(sum, 32);
    rs[qi] = 1.0f / sum;
  }

  // ctx^T = V^T @ P^T via 16x16x16 (P^T frags feed B-operand lane-for-lane)
  float4v cacc[2][2] = {};  // [df][qi]
  #pragma unroll
  for (int ks = 0; ks < 16; ++ks) {
    short4v pb[2];
    pb[0] = cvt4(s[ks][0]);
    pb[1] = cvt4(s[ks][1]);
    #pragma unroll
    for (int df = 0; df < 2; ++df) {
      const char* vb = vs + (size_t)(16 * ks + 4 * gq) * 80 + (df * 16 + ln15) * 2;
      short4v va;
      va[0] = *(const short*)(vb);
      va[1] = *(const short*)(vb + 80);
      va[2] = *(const short*)(vb + 160);
      va[3] = *(const short*)(vb + 240);
      cacc[df][0] = mfma16(va, pb[0], cacc[df][0]);
      cacc[df][1] = mfma16(va, pb[1], cacc[df][1]);
    }
  }

  // scale by 1/sum and store (d contiguous 4 -> 8B stores)
  #pragma unroll
  for (int qi = 0; qi < 2; ++qi)
    #pragma unroll
    for (int df = 0; df < 2; ++df) {
      short4v o;
      #pragma unroll
      for (int j = 0; j < 4; ++j) o[j] = (short)f2bf(cacc[df][qi][j] * rs[qi]);
      *(short4v*)(ctx + (size_t)(tok0 + q0 + qi * 16 + ln15) * 256 + head * 32 + df * 16 + 4 * gq) = o;
    }
}

// ---------------- row-wise LayerNorm in place (bf16), one wave per row ----------------
__global__ __launch_bounds__(256, 4)
void ln_rows(u16* __restrict__ x, const float* __restrict__ g, const float* __restrict__ b) {
  int row = blockIdx.x * 4 + (threadIdx.x >> 6);
  int lane = threadIdx.x & 63;
  u16* p = x + (size_t)row * 256 + lane * 4;
  short4v v = *(short4v*)p;
  float f[4];
  #pragma unroll
  for (int i = 0; i < 4; ++i) f[i] = bf2f((unsigned short)v[i]);
  float s = f[0] + f[1] + f[2] + f[3];
  float ss = f[0] * f[0] + f[1] * f[1] + f[2] * f[2] + f[3] * f[3];
  #pragma unroll
  for (int m = 1; m <= 32; m <<= 1) {
    s += __shfl_xor(s, m);
    ss += __shfl_xor(ss, m);
  }
  float mu = s * (1.f / 256.f);
  float var = ss * (1.f / 256.f) - mu * mu;
  float rstd = rsqrtf(var + 1e-5f);
  #pragma unroll
  for (int i = 0; i < 4; ++i) {
    int c = lane * 4 + i;
    float o = (f[i] - mu) * rstd * g[c] + b[c];
    v[i] = (short)f2bf(o);
  }
  *(short4v*)p = v;
}

// ---------------- fused FFN v2 + residual + LN2 ----------------
// out = LN2(x + relu(x@W1+b1)@W2 + b2).  x:[65536][256] bf16, W1t:[1024][256],
// W2t:[256][1024] bf16, out f32.  Block = 64 rows, 4 waves; wave owns 16 rows,
// x in registers, h1 stays in registers (swapped GEMM1 -> mfma16 A-frag).
// W1 chunk [32f][256k] via global_load_lds (swizzled); W2 chunk [256n][32f]
// reg-staged into 80B-padded LDS rows. Double-buffered, 1 barrier/chunk.
__global__ __launch_bounds__(256, 2)
void ffn_v2(const u16* __restrict__ X, const u16* __restrict__ W1t,
            const u16* __restrict__ W2t, const float* __restrict__ b1,
            const float* __restrict__ b2, const float* __restrict__ g2,
            const float* __restrict__ be2, float* __restrict__ out) {
  __shared__ alignas(16) char w1c[2][16384];   // [32 f][512B k], XOR-swizzled
  __shared__ alignas(16) char w2c[2][20480];   // [256 n][80B] (64B data + 16 pad)
  const int tid = threadIdx.x;
  const int w = tid >> 6, lane = tid & 63;
  const int ln15 = lane & 15, gq = lane >> 4;
  const int m0 = blockIdx.x * 64;
  const int xrow = m0 + w * 16 + ln15;

  // x rows in registers (B-frags for swapped GEMM1): 8 k-chunks of 32
  short8v xr[8];
  #pragma unroll
  for (int kc = 0; kc < 8; ++kc)
    xr[kc] = *(const short8v*)(X + (size_t)xrow * 256 + kc * 32 + gq * 8);

  float4v ff[16] = {};  // output acc: col = nt*16+ln15, row = w*16 + 4gq + j
  short8v w2r[4];       // W2 chunk staging regs

  const char* W1b = (const char*)W1t;
  const char* W2b = (const char*)W2t;

  // ---- staging helpers (c = chunk index 0..31) ----
  #define STAGE_W1(buf, c)                                                     \
    {                                                                          \
      _Pragma("unroll")                                                        \
      for (int p = 0; p < 4; ++p) {                                            \
        int L = p * 4096 + tid * 16;                                           \
        int r = L >> 9, colb = L & 511;                                        \
        async16(W1b + (size_t)((c) * 32 + r) * 512 + (colb ^ ((r & 7) << 4)),  \
                w1c[buf] + L);                                                 \
      }                                                                        \
    }
  #define LOAD_W2(c)                                                           \
    {                                                                          \
      _Pragma("unroll")                                                        \
      for (int p = 0; p < 4; ++p) {                                            \
        int idx = p * 4096 + tid * 16;                                         \
        int n = idx >> 6, off = idx & 63;                                      \
        w2r[p] = *(const short8v*)(W2b + (size_t)n * 2048 + (c) * 64 + off);   \
      }                                                                        \
    }
  #define WRITE_W2(buf)                                                        \
    {                                                                          \
      _Pragma("unroll")                                                        \
      for (int p = 0; p < 4; ++p) {                                            \
        int idx = p * 4096 + tid * 16;                                         \
        int n = idx >> 6, off = idx & 63;                                      \
        *(short8v*)(w2c[buf] + n * 80 + off) = w2r[p];                         \
      }                                                                        \
    }

  STAGE_W1(0, 0);
  LOAD_W2(0);
  WRITE_W2(0);
  __syncthreads();

  #pragma unroll 2
  for (int c = 0; c < 32; ++c) {
    const int buf = c & 1;
    if (c < 31) {
      STAGE_W1(buf ^ 1, c + 1);
      LOAD_W2(c + 1);
    }

    // GEMM1 (swapped): h1^T[f-tile][xrow] = W1 @ x^T, k = 256
    float4v g1[2] = {};
    #pragma unroll
    for (int kc = 0; kc < 8; ++kc) {
      #pragma unroll
      for (int ft = 0; ft < 2; ++ft) {
        int r = ft * 16 + ln15;
        short8v a = *(const short8v*)(w1c[buf] + r * 512 +
                                      ((kc * 64 + gq * 16) ^ ((r & 7) << 4)));
        g1[ft] = mfma32(a, xr[kc], g1[ft]);
      }
    }
    // bias + relu + pack: lane holds h1[row=ln15][f = c*32 + ft*16 + 4gq + j]
    short4v pa[2];
    #pragma unroll
    for (int ft = 0; ft < 2; ++ft) {
      #pragma unroll
      for (int j = 0; j < 4; ++j) {
        float v = g1[ft][j] + b1[c * 32 + ft * 16 + 4 * gq + j];
        v = v > 0.f ? v : 0.f;
        pa[ft][j] = (short)f2bf(v);
      }
    }
    // GEMM2: ff[row][n] += h1 @ W2chunk  (mfma16; pa is the A-frag directly)
    #pragma unroll
    for (int nt = 0; nt < 16; ++nt) {
      const char* base = w2c[buf] + (nt * 16 + ln15) * 80 + gq * 8;
      short4v b0 = *(const short4v*)(base);
      short4v b1f = *(const short4v*)(base + 32);
      ff[nt] = mfma16(pa[0], b0, ff[nt]);
      ff[nt] = mfma16(pa[1], b1f, ff[nt]);
    }

    if (c < 31) WRITE_W2(buf ^ 1);
    __syncthreads();
  }

  // ---- epilogue: + b2 + x residual, LN2 per row (16-lane reduce), f32 out ----
  #pragma unroll
  for (int j = 0; j < 4; ++j) {
    int r2 = m0 + w * 16 + 4 * gq + j;
    float sum = 0.f, sq = 0.f;
    #pragma unroll
    for (int nt = 0; nt < 16; ++nt) {
      int col = nt * 16 + ln15;
      float xv = bf2f(X[(size_t)r2 * 256 + col]);
      float v = ff[nt][j] + b2[col] + xv;
      ff[nt][j] = v;
      sum += v;
      sq += v * v;
    }
    #pragma unroll
    for (int m = 1; m <= 8; m <<= 1) {
      sum += __shfl_xor(sum, m);
      sq += __shfl_xor(sq, m);
    }
    float mu = sum * (1.f / 256.f);
    float var = sq * (1.f / 256.f) - mu * mu;
    float rstd = rsqrtf(var + 1e-5f);
    #pragma unroll
    for (int nt = 0; nt < 16; ++nt) {
      int col = nt * 16 + ln15;
      out[(size_t)r2 * 256 + col] = (ff[nt][j] - mu) * rstd * g2[col] + be2[col];
    }
  }
  #undef STAGE_W1
  #undef LOAD_W2
  #undef WRITE_W2
}

extern "C" void kernel_launch(void* const* d_in, const int* in_sizes, int n_in,
                              void* d_out, int out_size, void* d_ws, size_t ws_size,
                              hipStream_t stream) {
  (void)in_sizes; (void)n_in; (void)out_size;
  const float* query = (const float*)d_in[0];
  const float* kv    = (const float*)d_in[1];
  const float* Wqm = (const float*)d_in[2];  const float* bq = (const float*)d_in[3];
  const float* Wkm = (const float*)d_in[4];  const float* bk = (const float*)d_in[5];
  const float* Wvm = (const float*)d_in[6];  const float* bv = (const float*)d_in[7];
  const float* Wom = (const float*)d_in[8];  const float* bo = (const float*)d_in[9];
  const float* ln1g = (const float*)d_in[10]; const float* ln1b = (const float*)d_in[11];
  const float* W1m = (const float*)d_in[12]; const float* b1 = (const float*)d_in[13];
  const float* W2m = (const float*)d_in[14]; const float* b2 = (const float*)d_in[15];
  const float* ln2g = (const float*)d_in[16]; const float* ln2b = (const float*)d_in[17];
  float* out = (float*)d_out;

  char* ws = (char*)d_ws;
  const size_t MB = 1ull << 20;
  if (ws_size < 130 * MB) return;  // avoid OOB if workspace too small

  // lifetime-aliased layout (all bf16):
  u16* qbf  = (u16*)(ws);            // [0,32M)  input q bf16; dead after Q-proj
  u16* kvbf = (u16*)(ws + 32 * MB);  // [32,64M) input kv bf16; dead after V-proj
  u16* Vw   = (u16*)(ws);            // aliases qbf
  u16* ctxw = (u16*)(ws + 32 * MB);  // aliases kvbf
  u16* Qw   = (u16*)(ws + 64 * MB);  // dead after attn
  u16* xw   = (u16*)(ws + 64 * MB);  // aliases Qw
  u16* Kw   = (u16*)(ws + 96 * MB);
  char* wb = ws + 128 * MB;
  u16* Wqt = (u16*)(wb);
  u16* Wkt = (u16*)(wb + 131072);
  u16* Wvt = (u16*)(wb + 262144);
  u16* Wot = (u16*)(wb + 393216);
  u16* W1t = (u16*)(wb + 524288);
  u16* W2t = (u16*)(wb + 1048576);

  cvt_in<<<dim3(8192, 2), 256, 0, stream>>>(query, kv, qbf, kvbf);
  cvt_w<<<dim3(1024, 6), 256, 0, stream>>>(Wqm, Wkm, Wvm, Wom, W1m, W2m,
                                           Wqt, Wkt, Wvt, Wot, W1t, W2t);
  gemm128<false><<<dim3(512, 2), 256, 0, stream>>>(qbf,  Wqt, bq, nullptr, Qw, 65536, 256, 256);
  gemm128<false><<<dim3(512, 2), 256, 0, stream>>>(kvbf, Wkt, bk, nullptr, Kw, 65536, 256, 256);
  gemm128<false><<<dim3(512, 2), 256, 0, stream>>>(kvbf, Wvt, bv, nullptr, Vw, 65536, 256, 256);
  attn_kernel<<<dim3(4096), 256, 0, stream>>>(Qw, Kw, Vw, ctxw);
  gemm128<true><<<dim3(512, 2), 256, 0, stream>>>(ctxw, Wot, bo, query, xw, 65536, 256, 256);
  ln_rows<<<dim3(16384), 256, 0, stream>>>(xw, ln1g, ln1b);
  ffn_v2<<<dim3(1024), 256, 0, stream>>>(xw, W1t, W2t, b1, b2, ln2g, ln2b, out);
}